// Round 5
// baseline (1096.267 us; speedup 1.0000x reference)
//
#include <hip/hip_runtime.h>
#include <hip/hip_bf16.h>

typedef unsigned short u16;
typedef unsigned char uchar;
typedef unsigned long long u64;
typedef float f32x4 __attribute__((ext_vector_type(4)));
typedef int i8v __attribute__((ext_vector_type(8)));

#define FDIM 2048
#define NBLK 256
#define NCELL 126

__device__ __forceinline__ u16 f2b(float x) {
    __hip_bfloat16 h = __float2bfloat16(x);
    return __builtin_bit_cast(u16, h);
}
__device__ __forceinline__ float b2f(u16 u) {
    __hip_bfloat16 h = __builtin_bit_cast(__hip_bfloat16, u);
    return __bfloat162float(h);
}
__device__ __forceinline__ float sigm(float x) { return 1.0f / (1.0f + __expf(-x)); }
__device__ __forceinline__ float tanh_f(float x) { return 1.0f - 2.0f / (__expf(2.0f * x) + 1.0f); }

// OCP e4m3 encode (RNE), saturate to 448.
__device__ __forceinline__ unsigned f2fp8(float x) {
    unsigned u = __builtin_bit_cast(unsigned, x);
    unsigned s = (u >> 24) & 0x80u;
    unsigned mag = u & 0x7fffffffu;
    if (mag >= 0x43E80000u) return s | 0x7Eu;
    int e = (int)(mag >> 23) - 127;
    if (e >= -6) {
        unsigned m = mag + 0x7FFFFu + ((mag >> 20) & 1u);
        unsigned e8 = (m >> 23) - 127 + 7;
        unsigned m3 = (m >> 20) & 7u;
        if (e8 >= 16u) return s | 0x7Eu;
        return s | (e8 << 3) | m3;
    }
    float ax = __builtin_bit_cast(float, mag);
    int d = (int)__builtin_rintf(ax * 512.0f);
    return s | (unsigned)d;
}

// e2m1 (fp4) quantize of v (|v|<=6 after scaling): returns 4-bit code
__device__ __forceinline__ unsigned q_e2m1(float v) {
    unsigned s = (v < 0.f) ? 8u : 0u;
    float a = fabsf(v);
    unsigned q;
    if (a < 0.25f) q = 0;
    else if (a < 0.75f) q = 1;
    else if (a < 1.25f) q = 2;
    else if (a < 1.75f) q = 3;
    else if (a < 2.5f)  q = 4;
    else if (a < 3.5f)  q = 5;
    else if (a < 5.0f)  q = 6;
    else q = 7;
    return s | q;
}

// ---------------- weight pack: fp32 -> MX fp4 (E8M0 per-32 scales), MFMA fragment order ----------
// Wp4 layout: [bl][mat(4)][gp(2)][kt(16)][lane(64)] x 16B  (128 KB per block)
// scl layout: [bl][mat][gp][lane] x 16B (byte kt)
__global__ __launch_bounds__(256) void k_pack4(const float* __restrict__ W0, const float* __restrict__ W1,
                                               const float* __restrict__ W2, const float* __restrict__ W3,
                                               uchar* __restrict__ Wp4, uchar* __restrict__ scl) {
    __shared__ float lw[32][132];
    int idx = blockIdx.x;                 // [0, 256*4*16)
    int kt = idx & 15, mat = (idx >> 4) & 3, bl = idx >> 6;
    const float* src = mat == 0 ? W0 : mat == 1 ? W1 : mat == 2 ? W2 : W3;
    int tid = threadIdx.x;
    for (int i = tid; i < 32 * 32; i += 256) {
        int r = i >> 5, c4 = i & 31;
        const float* p = src + (size_t)((r >> 3) * 2048 + bl * 8 + (r & 7)) * 2048 + kt * 128 + c4 * 4;
        float4 v = *(const float4*)p;
        lw[r][c4 * 4 + 0] = v.x; lw[r][c4 * 4 + 1] = v.y;
        lw[r][c4 * 4 + 2] = v.z; lw[r][c4 * 4 + 3] = v.w;
    }
    __syncthreads();
    if (tid < 128) {
        int gp = tid >> 6, lane = tid & 63;
        int r = (2 * gp + ((lane & 15) >> 3)) * 8 + (lane & 7);
        int k0 = (lane >> 4) * 32;
        float mx = 0.f;
#pragma unroll
        for (int e = 0; e < 32; ++e) mx = fmaxf(mx, fabsf(lw[r][k0 + e]));
        int ee = -127;
        if (mx > 0.f) {
            ee = (int)ceilf(log2f(mx * (1.0f / 6.0f)));
            if (ee < -127) ee = -127;
            if (ee > 127) ee = 127;
        }
        float inv = exp2f((float)(-ee));
        unsigned wd[4];
#pragma unroll
        for (int d = 0; d < 4; ++d) {
            unsigned acc = 0;
#pragma unroll
            for (int bi = 0; bi < 4; ++bi) {
                float v0 = lw[r][k0 + d * 8 + 2 * bi] * inv;
                float v1 = lw[r][k0 + d * 8 + 2 * bi + 1] * inv;
                acc |= (q_e2m1(v0) << (bi * 8)) | (q_e2m1(v1) << (bi * 8 + 4));
            }
            wd[d] = acc;
        }
        size_t wo = (size_t)bl * 131072 + (((size_t)(mat * 2 + gp) * 16 + (size_t)kt) * 64 + lane) * 16;
        *(uint4*)(Wp4 + wo) = make_uint4(wd[0], wd[1], wd[2], wd[3]);
        scl[(((size_t)bl * 4 + mat) * 2 + gp) * 1024 + (size_t)lane * 16 + kt] = (uchar)(ee + 127);
    }
}

__global__ void k_bias(const float* __restrict__ bi0, const float* __restrict__ bh0,
                       const float* __restrict__ bi1, const float* __restrict__ bh1,
                       float* __restrict__ bias0, float* __restrict__ bias1) {
    int i = blockIdx.x * blockDim.x + threadIdx.x;
    if (i < 4 * FDIM) {
        bias0[i] = bi0[i] + bh0[i];
        bias1[i] = bi1[i] + bh1[i];
    }
}

// ---------------- input 1x1 conv -> seq layout [t][b][2048] fp8 (x4) ----------------
__global__ __launch_bounds__(256) void k_seqprep(const float* __restrict__ x,
                                                 const float* __restrict__ w_in,
                                                 const float* __restrict__ b_in,
                                                 uchar* __restrict__ seqb) {
    int h = blockIdx.x >> 4, b = blockIdx.x & 15;
    __shared__ float xs[256][32];
    __shared__ float wl[64][257];
    int tid = threadIdx.x;
    for (int i = tid; i < 256 * 32; i += 256) {
        int c = i >> 5, w = i & 31;
        xs[c][w] = x[(((size_t)b * 256 + c) * 32 + h) * 32 + w];
    }
    for (int i = tid; i < 64 * 256; i += 256) {
        int cb = i >> 8, c = i & 255;
        wl[cb][c] = w_in[i];
    }
    __syncthreads();
    int w = (tid * 8) >> 6, cb0 = (tid * 8) & 63;
    float acc[8];
#pragma unroll
    for (int j = 0; j < 8; ++j) acc[j] = b_in[cb0 + j];
    for (int c = 0; c < 256; ++c) {
        float xv = xs[c][w];
#pragma unroll
        for (int j = 0; j < 8; ++j) acc[j] += xv * wl[cb0 + j][c];
    }
    unsigned lo = 0, hi2 = 0;
#pragma unroll
    for (int j = 0; j < 4; ++j) lo |= f2fp8(acc[j] * 4.0f) << (j * 8);
#pragma unroll
    for (int j = 0; j < 4; ++j) hi2 |= f2fp8(acc[4 + j] * 4.0f) << (j * 8);
    *(uint2*)(seqb + ((size_t)h * 16 + b) * FDIM + tid * 8) = make_uint2(lo, hi2);
}

// ---------------- persistent LSTM: LDS-resident fp4 weights, epoch dataflow ----------------
__global__ __launch_bounds__(256, 1) void k_lstm(const uchar* __restrict__ Wp4,
                                                 const uchar* __restrict__ scl,
                                                 const float* __restrict__ bias0,
                                                 const float* __restrict__ bias1,
                                                 const uchar* __restrict__ seqb,
                                                 uchar* __restrict__ H0, uchar* __restrict__ H1,
                                                 u16* __restrict__ seqout,
                                                 unsigned* __restrict__ cnts, unsigned* __restrict__ epoch) {
    __shared__ uchar wlds[131072];            // [mat*2+gp][kt][lane*16]
    __shared__ float gbuf[4][16][16];
    const int tid = threadIdx.x, lane = tid & 63, w = tid >> 6;
    const int gp = w & 1, m = w >> 1;         // w = m*2+gp
    const int bl = blockIdx.x;
    const size_t BF = (size_t)16 * FDIM;

    // load this block's packed weights into LDS (once)
    {
        const uchar* src = Wp4 + (size_t)bl * 131072;
        for (int i = tid; i < 8192; i += 256)
            *(uint4*)(wlds + (size_t)i * 16) = *(const uint4*)(src + (size_t)i * 16);
    }
    // per-wave-lane scale regs (16 kt bytes per matrix)
    uint4 scl0 = *(const uint4*)(scl + (((size_t)bl * 4 + m) * 2 + gp) * 1024 + (size_t)lane * 16);
    uint4 scl1 = *(const uint4*)(scl + (((size_t)bl * 4 + 2 + m) * 2 + gp) * 1024 + (size_t)lane * 16);

    int f = tid & 7, col = bl * 8 + f;
    float bia[8];
    float cst0 = 0.f, cst1 = 0.f;
    if (tid < 128) {
#pragma unroll
        for (int g = 0; g < 4; ++g) {
            bia[g] = bias0[g * FDIM + col];
            bia[4 + g] = bias1[g * FDIM + col];
        }
    }
    __syncthreads();

    const int b16 = lane & 15, kq = lane >> 4;
    for (int c = 0; c < NCELL; ++c) {
        int s = c >> 1, isL1 = c & 1;
        const uchar* xsrc = isL1 ? (H0 + (size_t)(s + 1) * BF)
                          : (s < 32 ? (seqb + (size_t)s * BF) : (H1 + (size_t)s * BF));
        const uchar* hsrc = isL1 ? (H1 + (size_t)s * BF) : (H0 + (size_t)s * BF);
        const uchar* asrc = m ? hsrc : xsrc;
        // wave-asymmetric epoch waits: hh needs cell c-2 done (epoch>=c-1); ih needs c-1 (>=c); encode-ih none
        int waitE = m ? (c - 1) : ((isL1 || s >= 32) ? c : 0);
        if (waitE > 0) {
            if (lane == 0)
                while ((int)__hip_atomic_load(epoch, __ATOMIC_RELAXED, __HIP_MEMORY_SCOPE_AGENT) < waitE)
                    __builtin_amdgcn_s_sleep(2);
            asm volatile("" ::: "memory");
        }
        int mat = isL1 * 2 + m;
        const uchar* ap = asrc + b16 * 2048 + kq * 32;
        const uchar* bp = wlds + (size_t)(mat * 2 + gp) * 16384 + lane * 16;
        unsigned sdw[4];
        { uint4 sv = isL1 ? scl1 : scl0; sdw[0] = sv.x; sdw[1] = sv.y; sdw[2] = sv.z; sdw[3] = sv.w; }

        f32x4 acc0 = {0.f, 0.f, 0.f, 0.f}, acc1 = {0.f, 0.f, 0.f, 0.f};
        uint4 A[8][2];
#pragma unroll
        for (int kt = 0; kt < 8; ++kt) {
            A[kt][0] = *(const uint4*)(ap + kt * 128);
            A[kt][1] = *(const uint4*)(ap + kt * 128 + 16);
        }
#pragma unroll
        for (int g = 0; g < 4; ++g) {
#pragma unroll
            for (int j = 0; j < 4; ++j) {
                const int kt = 4 * g + j;
                const int slot = kt & 7;
                uint4 alo = A[slot][0], ahi = A[slot][1];
                uint4 bb = *(const uint4*)(bp + kt * 1024);
                i8v av = {(int)alo.x, (int)alo.y, (int)alo.z, (int)alo.w,
                          (int)ahi.x, (int)ahi.y, (int)ahi.z, (int)ahi.w};
                i8v bv = {(int)bb.x, (int)bb.y, (int)bb.z, (int)bb.w, 0, 0, 0, 0};
                f32x4& ac = (j & 1) ? acc1 : acc0;
                if (j == 0)      ac = __builtin_amdgcn_mfma_scale_f32_16x16x128_f8f6f4(av, bv, ac, 0, 4, 0, 127, 0, (int)sdw[g]);
                else if (j == 1) ac = __builtin_amdgcn_mfma_scale_f32_16x16x128_f8f6f4(av, bv, ac, 0, 4, 0, 127, 1, (int)sdw[g]);
                else if (j == 2) ac = __builtin_amdgcn_mfma_scale_f32_16x16x128_f8f6f4(av, bv, ac, 0, 4, 0, 127, 2, (int)sdw[g]);
                else             ac = __builtin_amdgcn_mfma_scale_f32_16x16x128_f8f6f4(av, bv, ac, 0, 4, 0, 127, 3, (int)sdw[g]);
                if (g < 2) {  // prefetch kt+8 into same slot
                    A[slot][0] = *(const uint4*)(ap + (kt + 8) * 128);
                    A[slot][1] = *(const uint4*)(ap + (kt + 8) * 128 + 16);
                }
            }
        }
        f32x4 acc = acc0 + acc1;
#pragma unroll
        for (int i = 0; i < 4; ++i) gbuf[w][kq * 4 + i][b16] = acc[i];
        __syncthreads();   // S1

        if (tid < 128) {
            int b = tid >> 3;
            const float* bb2 = bia + (isL1 ? 4 : 0);
            float gv[4];
#pragma unroll
            for (int g2 = 0; g2 < 4; ++g2) {
                int gpp = g2 >> 1, jl = ((g2 & 1) << 3) | f;
                gv[g2] = (gbuf[gpp][b][jl] + gbuf[2 + gpp][b][jl]) * 0.25f + bb2[g2];
            }
            float co = isL1 ? cst1 : cst0;
            float cn = sigm(gv[1]) * co + sigm(gv[0]) * tanh_f(gv[2]);
            float hn = sigm(gv[3]) * tanh_f(cn);
            if (isL1) cst1 = cn; else cst0 = cn;
            uchar* hdst = (isL1 ? H1 : H0) + (size_t)(s + 1) * BF;
            __hip_atomic_store(hdst + (size_t)b * FDIM + col, (uchar)f2fp8(hn * 4.0f),
                               __ATOMIC_RELAXED, __HIP_MEMORY_SCOPE_AGENT);
            if (isL1 && s >= 31) seqout[(size_t)(s - 31) * BF + (size_t)b * FDIM + col] = f2b(hn);
        }
        __syncthreads();   // S2: drains h-stores (vmcnt 0) before arrival
        if (tid == 192) {  // wave-3 lane0: its next-cell wait overlaps the RMW chain
            unsigned old = __hip_atomic_fetch_add(cnts + (size_t)(bl >> 4) * 32, 1u,
                                                  __ATOMIC_RELAXED, __HIP_MEMORY_SCOPE_AGENT);
            if ((old & 15) == 15) {
                unsigned rold = __hip_atomic_fetch_add(cnts + (size_t)16 * 32, 1u,
                                                       __ATOMIC_RELAXED, __HIP_MEMORY_SCOPE_AGENT);
                if ((rold & 15) == 15)
                    __hip_atomic_store(epoch, (unsigned)(c + 1),
                                       __ATOMIC_RELAXED, __HIP_MEMORY_SCOPE_AGENT);
            }
        }
    }
}

// ---------------- copy x into top half of output ----------------
__global__ void k_copyx(const float* __restrict__ x, float* __restrict__ out) {
    size_t n = (size_t)4096 * 256;
    size_t stride = (size_t)gridDim.x * blockDim.x;
    for (size_t i = (size_t)blockIdx.x * blockDim.x + threadIdx.x; i < n; i += stride) {
        size_t bc = i >> 8, r = i & 255;
        ((float4*)out)[bc * 512 + r] = ((const float4*)x)[i];
    }
}

// ---------------- output 1x1 conv into bottom half ----------------
__global__ __launch_bounds__(256) void k_convout(const u16* __restrict__ seqout,
                                                 const float* __restrict__ w_out,
                                                 const float* __restrict__ b_out,
                                                 float* __restrict__ out) {
    int s = blockIdx.x >> 4, b = blockIdx.x & 15;
    __shared__ float srow[2048];
    int tid = threadIdx.x;
    for (int i = tid; i < 2048; i += 256) srow[i] = b2f(seqout[((size_t)s * 16 + b) * FDIM + i]);
    __syncthreads();
    int o = tid;
    float bo = b_out[o];
    float wreg[64];
#pragma unroll
    for (int cb = 0; cb < 64; ++cb) wreg[cb] = w_out[o * 64 + cb];
    for (int w4 = 0; w4 < 8; ++w4) {
        float ac0 = bo, ac1 = bo, ac2 = bo, ac3 = bo;
#pragma unroll
        for (int cb = 0; cb < 64; ++cb) {
            float wv = wreg[cb];
            ac0 += srow[(w4 * 4 + 0) * 64 + cb] * wv;
            ac1 += srow[(w4 * 4 + 1) * 64 + cb] * wv;
            ac2 += srow[(w4 * 4 + 2) * 64 + cb] * wv;
            ac3 += srow[(w4 * 4 + 3) * 64 + cb] * wv;
        }
        float4 v; v.x = ac0; v.y = ac1; v.z = ac2; v.w = ac3;
        *(float4*)&out[(((size_t)b * 256 + o) * 64 + 32 + s) * 32 + w4 * 4] = v;
    }
}

extern "C" void kernel_launch(void* const* d_in, const int* in_sizes, int n_in,
                              void* d_out, int out_size, void* d_ws, size_t ws_size,
                              hipStream_t stream) {
    const float* x    = (const float*)d_in[0];
    const float* w_in = (const float*)d_in[1];
    const float* b_in = (const float*)d_in[2];
    const float* Wih0 = (const float*)d_in[3];
    const float* Whh0 = (const float*)d_in[4];
    const float* bih0 = (const float*)d_in[5];
    const float* bhh0 = (const float*)d_in[6];
    const float* Wih1 = (const float*)d_in[7];
    const float* Whh1 = (const float*)d_in[8];
    const float* bih1 = (const float*)d_in[9];
    const float* bhh1 = (const float*)d_in[10];
    const float* wout = (const float*)d_in[11];
    const float* bout = (const float*)d_in[12];
    float* out = (float*)d_out;
    char* ws = (char*)d_ws;
    const size_t BF = (size_t)16 * FDIM;

    uchar* Wp4 = (uchar*)ws;
    size_t off = (size_t)NBLK * 131072;                       // 32 MiB packed fp4 weights
    uchar* scl = (uchar*)(ws + off); off += (size_t)NBLK * 4 * 2 * 1024;   // 2 MiB scales
    float* bias0 = (float*)(ws + off); off += 4 * FDIM * 4;
    float* bias1 = (float*)(ws + off); off += 4 * FDIM * 4;
    uchar* seqb = (uchar*)(ws + off); off += (size_t)32 * BF;              // 1 MiB
    u16* seqout = (u16*)(ws + off); off += (size_t)32 * BF * 2;            // 2 MiB
    uchar* H0 = (uchar*)(ws + off); off += (size_t)64 * BF;                // 2 MiB (rotating slots)
    uchar* H1 = (uchar*)(ws + off); off += (size_t)64 * BF;                // 2 MiB
    off = (off + 127) & ~(size_t)127;
    unsigned* cnts = (unsigned*)(ws + off); size_t cntoff = off; off += 17 * 32 * 4;
    unsigned* epoch = (unsigned*)(ws + off); off += 128;

    // zero: H0 slot0, H1 slot0, barrier counters + epoch
    hipMemsetAsync(H0, 0, BF, stream);
    hipMemsetAsync(H1, 0, BF, stream);
    hipMemsetAsync(ws + cntoff, 0, off - cntoff, stream);

    k_pack4<<<256 * 4 * 16, 256, 0, stream>>>(Wih0, Whh0, Wih1, Whh1, Wp4, scl);
    k_bias<<<32, 256, 0, stream>>>(bih0, bhh0, bih1, bhh1, bias0, bias1);
    k_seqprep<<<512, 256, 0, stream>>>(x, w_in, b_in, seqb);
    k_lstm<<<NBLK, 256, 0, stream>>>(Wp4, scl, bias0, bias1, seqb, H0, H1, seqout, cnts, epoch);
    k_copyx<<<2048, 256, 0, stream>>>(x, out);
    k_convout<<<512, 256, 0, stream>>>(seqout, wout, bout, out);
}

// Round 6
// 1015.237 us; speedup vs baseline: 1.0798x; 1.0798x over previous
//
#include <hip/hip_runtime.h>
#include <hip/hip_bf16.h>

typedef unsigned short u16;
typedef unsigned char uchar;
typedef unsigned long long u64;
typedef float f32x4 __attribute__((ext_vector_type(4)));
typedef int i8v __attribute__((ext_vector_type(8)));

#define FDIM 2048
#define NBLK 256
#define NCELL 126

__device__ __forceinline__ u16 f2b(float x) {
    __hip_bfloat16 h = __float2bfloat16(x);
    return __builtin_bit_cast(u16, h);
}
__device__ __forceinline__ float b2f(u16 u) {
    __hip_bfloat16 h = __builtin_bit_cast(__hip_bfloat16, u);
    return __bfloat162float(h);
}
__device__ __forceinline__ float sigm(float x) { return 1.0f / (1.0f + __expf(-x)); }
__device__ __forceinline__ float tanh_f(float x) { return 1.0f - 2.0f / (__expf(2.0f * x) + 1.0f); }

// OCP e4m3 encode (RNE), saturate to 448.
__device__ __forceinline__ unsigned f2fp8(float x) {
    unsigned u = __builtin_bit_cast(unsigned, x);
    unsigned s = (u >> 24) & 0x80u;
    unsigned mag = u & 0x7fffffffu;
    if (mag >= 0x43E80000u) return s | 0x7Eu;
    int e = (int)(mag >> 23) - 127;
    if (e >= -6) {
        unsigned m = mag + 0x7FFFFu + ((mag >> 20) & 1u);
        unsigned e8 = (m >> 23) - 127 + 7;
        unsigned m3 = (m >> 20) & 7u;
        if (e8 >= 16u) return s | 0x7Eu;
        return s | (e8 << 3) | m3;
    }
    float ax = __builtin_bit_cast(float, mag);
    int d = (int)__builtin_rintf(ax * 512.0f);
    return s | (unsigned)d;
}

// e2m1 (fp4) quantize of v (|v|<=6 after scaling): returns 4-bit code
__device__ __forceinline__ unsigned q_e2m1(float v) {
    unsigned s = (v < 0.f) ? 8u : 0u;
    float a = fabsf(v);
    unsigned q;
    if (a < 0.25f) q = 0;
    else if (a < 0.75f) q = 1;
    else if (a < 1.25f) q = 2;
    else if (a < 1.75f) q = 3;
    else if (a < 2.5f)  q = 4;
    else if (a < 3.5f)  q = 5;
    else if (a < 5.0f)  q = 6;
    else q = 7;
    return s | q;
}

// ---------------- weight pack: fp32 -> MX fp4 (E8M0 per-32 scales), MFMA fragment order ----------
// Wp4 layout: [bl][mat(4)][gp(2)][kt(16)][lane(64)] x 16B  (128 KB per block)
// scl layout: [bl][mat][gp][lane] x 16B (byte kt)
__global__ __launch_bounds__(256) void k_pack4(const float* __restrict__ W0, const float* __restrict__ W1,
                                               const float* __restrict__ W2, const float* __restrict__ W3,
                                               uchar* __restrict__ Wp4, uchar* __restrict__ scl) {
    __shared__ float lw[32][132];
    int idx = blockIdx.x;                 // [0, 256*4*16)
    int kt = idx & 15, mat = (idx >> 4) & 3, bl = idx >> 6;
    const float* src = mat == 0 ? W0 : mat == 1 ? W1 : mat == 2 ? W2 : W3;
    int tid = threadIdx.x;
    for (int i = tid; i < 32 * 32; i += 256) {
        int r = i >> 5, c4 = i & 31;
        const float* p = src + (size_t)((r >> 3) * 2048 + bl * 8 + (r & 7)) * 2048 + kt * 128 + c4 * 4;
        float4 v = *(const float4*)p;
        lw[r][c4 * 4 + 0] = v.x; lw[r][c4 * 4 + 1] = v.y;
        lw[r][c4 * 4 + 2] = v.z; lw[r][c4 * 4 + 3] = v.w;
    }
    __syncthreads();
    if (tid < 128) {
        int gp = tid >> 6, lane = tid & 63;
        int r = (2 * gp + ((lane & 15) >> 3)) * 8 + (lane & 7);
        int k0 = (lane >> 4) * 32;
        float mx = 0.f;
#pragma unroll
        for (int e = 0; e < 32; ++e) mx = fmaxf(mx, fabsf(lw[r][k0 + e]));
        int ee = -127;
        if (mx > 0.f) {
            ee = (int)ceilf(log2f(mx * (1.0f / 6.0f)));
            if (ee < -127) ee = -127;
            if (ee > 127) ee = 127;
        }
        float inv = exp2f((float)(-ee));
        unsigned wd[4];
#pragma unroll
        for (int d = 0; d < 4; ++d) {
            unsigned acc = 0;
#pragma unroll
            for (int bi = 0; bi < 4; ++bi) {
                float v0 = lw[r][k0 + d * 8 + 2 * bi] * inv;
                float v1 = lw[r][k0 + d * 8 + 2 * bi + 1] * inv;
                acc |= (q_e2m1(v0) << (bi * 8)) | (q_e2m1(v1) << (bi * 8 + 4));
            }
            wd[d] = acc;
        }
        size_t wo = (size_t)bl * 131072 + (((size_t)(mat * 2 + gp) * 16 + (size_t)kt) * 64 + lane) * 16;
        *(uint4*)(Wp4 + wo) = make_uint4(wd[0], wd[1], wd[2], wd[3]);
        scl[(((size_t)bl * 4 + mat) * 2 + gp) * 1024 + (size_t)lane * 16 + kt] = (uchar)(ee + 127);
    }
}

__global__ void k_bias(const float* __restrict__ bi0, const float* __restrict__ bh0,
                       const float* __restrict__ bi1, const float* __restrict__ bh1,
                       float* __restrict__ bias0, float* __restrict__ bias1) {
    int i = blockIdx.x * blockDim.x + threadIdx.x;
    if (i < 4 * FDIM) {
        bias0[i] = bi0[i] + bh0[i];
        bias1[i] = bi1[i] + bh1[i];
    }
}

// ---------------- input 1x1 conv -> seq layout [t][b][2048] fp8 (x4) ----------------
__global__ __launch_bounds__(256) void k_seqprep(const float* __restrict__ x,
                                                 const float* __restrict__ w_in,
                                                 const float* __restrict__ b_in,
                                                 uchar* __restrict__ seqb) {
    int h = blockIdx.x >> 4, b = blockIdx.x & 15;
    __shared__ float xs[256][32];
    __shared__ float wl[64][257];
    int tid = threadIdx.x;
    for (int i = tid; i < 256 * 32; i += 256) {
        int c = i >> 5, w = i & 31;
        xs[c][w] = x[(((size_t)b * 256 + c) * 32 + h) * 32 + w];
    }
    for (int i = tid; i < 64 * 256; i += 256) {
        int cb = i >> 8, c = i & 255;
        wl[cb][c] = w_in[i];
    }
    __syncthreads();
    int w = (tid * 8) >> 6, cb0 = (tid * 8) & 63;
    float acc[8];
#pragma unroll
    for (int j = 0; j < 8; ++j) acc[j] = b_in[cb0 + j];
    for (int c = 0; c < 256; ++c) {
        float xv = xs[c][w];
#pragma unroll
        for (int j = 0; j < 8; ++j) acc[j] += xv * wl[cb0 + j][c];
    }
    unsigned lo = 0, hi2 = 0;
#pragma unroll
    for (int j = 0; j < 4; ++j) lo |= f2fp8(acc[j] * 4.0f) << (j * 8);
#pragma unroll
    for (int j = 0; j < 4; ++j) hi2 |= f2fp8(acc[4 + j] * 4.0f) << (j * 8);
    *(uint2*)(seqb + ((size_t)h * 16 + b) * FDIM + tid * 8) = make_uint2(lo, hi2);
}

// ---------------- persistent LSTM: LDS-resident fp4 weights, 1-hop counter barrier ----------------
// 8 waves: gp = w&1 (gate pair), m = (w>>1)&1 (ih/hh), kh = w>>2 (K-half)
__global__ __launch_bounds__(512, 1) void k_lstm(const uchar* __restrict__ Wp4,
                                                 const uchar* __restrict__ scl,
                                                 const float* __restrict__ bias0,
                                                 const float* __restrict__ bias1,
                                                 const uchar* __restrict__ seqb,
                                                 uchar* __restrict__ H0, uchar* __restrict__ H1,
                                                 u16* __restrict__ seqout,
                                                 unsigned* __restrict__ cnts) {
    __shared__ uchar wlds[131072];            // [mat*2+gp][kt][lane*16]
    __shared__ float gbuf[8][16][16];
    __shared__ u64 hs_st[16];
    const int tid = threadIdx.x, lane = tid & 63, w = tid >> 6;
    const int gp = w & 1, m = (w >> 1) & 1, kh = w >> 2;
    const int bl = blockIdx.x;
    const size_t BF = (size_t)16 * FDIM;

    // load this block's packed weights into LDS (once)
    {
        const uchar* src = Wp4 + (size_t)bl * 131072;
        for (int i = tid; i < 8192; i += 512)
            *(uint4*)(wlds + (size_t)i * 16) = *(const uint4*)(src + (size_t)i * 16);
    }
    // per-wave-lane scale regs (16 kt bytes per matrix; this wave uses its kh half)
    uint4 scl0 = *(const uint4*)(scl + (((size_t)bl * 4 + m) * 2 + gp) * 1024 + (size_t)lane * 16);
    uint4 scl1 = *(const uint4*)(scl + (((size_t)bl * 4 + 2 + m) * 2 + gp) * 1024 + (size_t)lane * 16);

    int f = tid & 7, col = bl * 8 + f;
    float bia[8];
    float cst0 = 0.f, cst1 = 0.f;
    if (tid < 128) {
#pragma unroll
        for (int g = 0; g < 4; ++g) {
            bia[g] = bias0[g * FDIM + col];
            bia[4 + g] = bias1[g * FDIM + col];
        }
    }
    __syncthreads();

    const int b16 = lane & 15, kq = lane >> 4;
    for (int c = 0; c < NCELL; ++c) {
        int s = c >> 1, isL1 = c & 1;
        const uchar* xsrc = isL1 ? (H0 + (size_t)(s + 1) * BF)
                          : (s < 32 ? (seqb + (size_t)s * BF) : (H1 + (size_t)s * BF));
        const uchar* hsrc = isL1 ? (H1 + (size_t)s * BF) : (H0 + (size_t)s * BF);
        const uchar* asrc = m ? hsrc : xsrc;
        // direct group-counter wait: "cells <= X done" <=> all 16 counters >= 16*(X+1)
        // ih (m=0) needs X=c-1 -> 16*c ; hh (m=1) needs X=c-2 -> 16*(c-1); encode-L0 ih: none
        int tgt = m ? (c - 1) : ((isL1 || s >= 32) ? c : 0);
        if (tgt > 0) {
            unsigned need = 16u * (unsigned)tgt;
            if (lane < 16) {
                while (__hip_atomic_load(cnts + (size_t)lane * 32,
                                         __ATOMIC_RELAXED, __HIP_MEMORY_SCOPE_AGENT) < need)
                    __builtin_amdgcn_s_sleep(1);
            }
        }
        asm volatile("" ::: "memory");

        int mat = isL1 * 2 + m;
        const uchar* ap = asrc + b16 * 2048 + kq * 32;
        const uchar* bp = wlds + (size_t)(mat * 2 + gp) * 16384 + lane * 16;
        uint4 sv = isL1 ? scl1 : scl0;
        unsigned sw0 = kh ? sv.z : sv.x;
        unsigned sw1 = kh ? sv.w : sv.y;

        // preload this wave's 8 A-fragments (its K-half), 16 loads in flight
        uint4 A[8][2];
#pragma unroll
        for (int t = 0; t < 8; ++t) {
            A[t][0] = *(const uint4*)(ap + (kh * 8 + t) * 128);
            A[t][1] = *(const uint4*)(ap + (kh * 8 + t) * 128 + 16);
        }
        f32x4 acc0 = {0.f, 0.f, 0.f, 0.f}, acc1 = {0.f, 0.f, 0.f, 0.f};
#define MF(T, SW, J)                                                                   \
        {                                                                              \
            uint4 alo = A[T][0], ahi = A[T][1];                                        \
            uint4 bb = *(const uint4*)(bp + (kh * 8 + (T)) * 1024);                    \
            i8v av = {(int)alo.x, (int)alo.y, (int)alo.z, (int)alo.w,                  \
                      (int)ahi.x, (int)ahi.y, (int)ahi.z, (int)ahi.w};                 \
            i8v bv = {(int)bb.x, (int)bb.y, (int)bb.z, (int)bb.w, 0, 0, 0, 0};         \
            if ((T) & 1)                                                               \
                acc1 = __builtin_amdgcn_mfma_scale_f32_16x16x128_f8f6f4(               \
                    av, bv, acc1, 0, 4, 0, 127, J, (int)(SW));                         \
            else                                                                       \
                acc0 = __builtin_amdgcn_mfma_scale_f32_16x16x128_f8f6f4(               \
                    av, bv, acc0, 0, 4, 0, 127, J, (int)(SW));                         \
        }
        MF(0, sw0, 0); MF(1, sw0, 1); MF(2, sw0, 2); MF(3, sw0, 3);
        MF(4, sw1, 0); MF(5, sw1, 1); MF(6, sw1, 2); MF(7, sw1, 3);
#undef MF
        f32x4 acc = acc0 + acc1;
#pragma unroll
        for (int i = 0; i < 4; ++i) gbuf[w][kq * 4 + i][b16] = acc[i];
        __syncthreads();   // S1

        if (tid < 128) {
            int b = tid >> 3;
            const float* bb2 = bia + (isL1 ? 4 : 0);
            float gv[4];
#pragma unroll
            for (int g2 = 0; g2 < 4; ++g2) {
                int gpp = g2 >> 1, jl = ((g2 & 1) << 3) | f;
                gv[g2] = (gbuf[gpp][b][jl] + gbuf[gpp + 2][b][jl]
                        + gbuf[gpp + 4][b][jl] + gbuf[gpp + 6][b][jl]) * 0.25f + bb2[g2];
            }
            float co = isL1 ? cst1 : cst0;
            float cn = sigm(gv[1]) * co + sigm(gv[0]) * tanh_f(gv[2]);
            float hn = sigm(gv[3]) * tanh_f(cn);
            if (isL1) cst1 = cn; else cst0 = cn;
            ((uchar*)&hs_st[b])[f] = (uchar)f2fp8(hn * 4.0f);
            if (isL1 && s >= 31) seqout[(size_t)(s - 31) * BF + (size_t)b * FDIM + col] = f2b(hn);
        }
        __syncthreads();   // S2: hs_st complete
        if (tid < 16) {
            uchar* hdst = (isL1 ? H1 : H0) + (size_t)(s + 1) * BF;
            __hip_atomic_store((u64*)(hdst + (size_t)tid * FDIM + bl * 8), hs_st[tid],
                               __ATOMIC_RELAXED, __HIP_MEMORY_SCOPE_AGENT);
        }
        __syncthreads();   // S3: h-stores acked at L3 (vmcnt drain) before arrival
        if (tid == 0)
            __hip_atomic_fetch_add(cnts + (size_t)(bl >> 4) * 32, 1u,
                                   __ATOMIC_RELAXED, __HIP_MEMORY_SCOPE_AGENT);
    }
}

// ---------------- copy x into top half of output ----------------
__global__ void k_copyx(const float* __restrict__ x, float* __restrict__ out) {
    size_t n = (size_t)4096 * 256;
    size_t stride = (size_t)gridDim.x * blockDim.x;
    for (size_t i = (size_t)blockIdx.x * blockDim.x + threadIdx.x; i < n; i += stride) {
        size_t bc = i >> 8, r = i & 255;
        ((float4*)out)[bc * 512 + r] = ((const float4*)x)[i];
    }
}

// ---------------- output 1x1 conv into bottom half ----------------
__global__ __launch_bounds__(256) void k_convout(const u16* __restrict__ seqout,
                                                 const float* __restrict__ w_out,
                                                 const float* __restrict__ b_out,
                                                 float* __restrict__ out) {
    int s = blockIdx.x >> 4, b = blockIdx.x & 15;
    __shared__ float srow[2048];
    int tid = threadIdx.x;
    for (int i = tid; i < 2048; i += 256) srow[i] = b2f(seqout[((size_t)s * 16 + b) * FDIM + i]);
    __syncthreads();
    int o = tid;
    float bo = b_out[o];
    float wreg[64];
#pragma unroll
    for (int cb = 0; cb < 64; ++cb) wreg[cb] = w_out[o * 64 + cb];
    for (int w4 = 0; w4 < 8; ++w4) {
        float ac0 = bo, ac1 = bo, ac2 = bo, ac3 = bo;
#pragma unroll
        for (int cb = 0; cb < 64; ++cb) {
            float wv = wreg[cb];
            ac0 += srow[(w4 * 4 + 0) * 64 + cb] * wv;
            ac1 += srow[(w4 * 4 + 1) * 64 + cb] * wv;
            ac2 += srow[(w4 * 4 + 2) * 64 + cb] * wv;
            ac3 += srow[(w4 * 4 + 3) * 64 + cb] * wv;
        }
        float4 v; v.x = ac0; v.y = ac1; v.z = ac2; v.w = ac3;
        *(float4*)&out[(((size_t)b * 256 + o) * 64 + 32 + s) * 32 + w4 * 4] = v;
    }
}

extern "C" void kernel_launch(void* const* d_in, const int* in_sizes, int n_in,
                              void* d_out, int out_size, void* d_ws, size_t ws_size,
                              hipStream_t stream) {
    const float* x    = (const float*)d_in[0];
    const float* w_in = (const float*)d_in[1];
    const float* b_in = (const float*)d_in[2];
    const float* Wih0 = (const float*)d_in[3];
    const float* Whh0 = (const float*)d_in[4];
    const float* bih0 = (const float*)d_in[5];
    const float* bhh0 = (const float*)d_in[6];
    const float* Wih1 = (const float*)d_in[7];
    const float* Whh1 = (const float*)d_in[8];
    const float* bih1 = (const float*)d_in[9];
    const float* bhh1 = (const float*)d_in[10];
    const float* wout = (const float*)d_in[11];
    const float* bout = (const float*)d_in[12];
    float* out = (float*)d_out;
    char* ws = (char*)d_ws;
    const size_t BF = (size_t)16 * FDIM;

    uchar* Wp4 = (uchar*)ws;
    size_t off = (size_t)NBLK * 131072;                       // 32 MiB packed fp4 weights
    uchar* scl = (uchar*)(ws + off); off += (size_t)NBLK * 4 * 2 * 1024;   // 2 MiB scales
    float* bias0 = (float*)(ws + off); off += 4 * FDIM * 4;
    float* bias1 = (float*)(ws + off); off += 4 * FDIM * 4;
    uchar* seqb = (uchar*)(ws + off); off += (size_t)32 * BF;              // 1 MiB
    u16* seqout = (u16*)(ws + off); off += (size_t)32 * BF * 2;            // 2 MiB
    uchar* H0 = (uchar*)(ws + off); off += (size_t)64 * BF;                // 2 MiB (rotating slots)
    uchar* H1 = (uchar*)(ws + off); off += (size_t)64 * BF;                // 2 MiB
    off = (off + 127) & ~(size_t)127;
    unsigned* cnts = (unsigned*)(ws + off); size_t cntoff = off; off += 16 * 32 * 4;

    // zero: H0 slot0, H1 slot0, barrier counters
    hipMemsetAsync(H0, 0, BF, stream);
    hipMemsetAsync(H1, 0, BF, stream);
    hipMemsetAsync(ws + cntoff, 0, off - cntoff, stream);

    k_pack4<<<256 * 4 * 16, 256, 0, stream>>>(Wih0, Whh0, Wih1, Whh1, Wp4, scl);
    k_bias<<<32, 256, 0, stream>>>(bih0, bhh0, bih1, bhh1, bias0, bias1);
    k_seqprep<<<512, 256, 0, stream>>>(x, w_in, b_in, seqb);
    k_lstm<<<NBLK, 512, 0, stream>>>(Wp4, scl, bias0, bias1, seqb, H0, H1, seqout, cnts);
    k_copyx<<<2048, 256, 0, stream>>>(x, out);
    k_convout<<<512, 256, 0, stream>>>(seqout, wout, bout, out);
}

// Round 7
// 875.746 us; speedup vs baseline: 1.2518x; 1.1593x over previous
//
#include <hip/hip_runtime.h>
#include <hip/hip_bf16.h>

typedef unsigned short u16;
typedef unsigned char uchar;
typedef unsigned long long u64;
typedef float f32x4 __attribute__((ext_vector_type(4)));
typedef int i8v __attribute__((ext_vector_type(8)));

#define FDIM 2048
#define NBLK 256
#define NCELL 126

__device__ __forceinline__ u16 f2b(float x) {
    __hip_bfloat16 h = __float2bfloat16(x);
    return __builtin_bit_cast(u16, h);
}
__device__ __forceinline__ float b2f(u16 u) {
    __hip_bfloat16 h = __builtin_bit_cast(__hip_bfloat16, u);
    return __bfloat162float(h);
}
__device__ __forceinline__ float sigm(float x) { return 1.0f / (1.0f + __expf(-x)); }
__device__ __forceinline__ float tanh_f(float x) { return 1.0f - 2.0f / (__expf(2.0f * x) + 1.0f); }

// OCP e4m3 encode (RNE), saturate to 448.
__device__ __forceinline__ unsigned f2fp8(float x) {
    unsigned u = __builtin_bit_cast(unsigned, x);
    unsigned s = (u >> 24) & 0x80u;
    unsigned mag = u & 0x7fffffffu;
    if (mag >= 0x43E80000u) return s | 0x7Eu;
    int e = (int)(mag >> 23) - 127;
    if (e >= -6) {
        unsigned m = mag + 0x7FFFFu + ((mag >> 20) & 1u);
        unsigned e8 = (m >> 23) - 127 + 7;
        unsigned m3 = (m >> 20) & 7u;
        if (e8 >= 16u) return s | 0x7Eu;
        return s | (e8 << 3) | m3;
    }
    float ax = __builtin_bit_cast(float, mag);
    int d = (int)__builtin_rintf(ax * 512.0f);
    return s | (unsigned)d;
}

// e2m1 (fp4) quantize of v (|v|<=6 after scaling): returns 4-bit code
__device__ __forceinline__ unsigned q_e2m1(float v) {
    unsigned s = (v < 0.f) ? 8u : 0u;
    float a = fabsf(v);
    unsigned q;
    if (a < 0.25f) q = 0;
    else if (a < 0.75f) q = 1;
    else if (a < 1.25f) q = 2;
    else if (a < 1.75f) q = 3;
    else if (a < 2.5f)  q = 4;
    else if (a < 3.5f)  q = 5;
    else if (a < 5.0f)  q = 6;
    else q = 7;
    return s | q;
}

// ---------------- weight pack: fp32 -> MX fp4 (E8M0 per-32 scales), MFMA fragment order ----------
__global__ __launch_bounds__(256) void k_pack4(const float* __restrict__ W0, const float* __restrict__ W1,
                                               const float* __restrict__ W2, const float* __restrict__ W3,
                                               uchar* __restrict__ Wp4, uchar* __restrict__ scl) {
    __shared__ float lw[32][132];
    int idx = blockIdx.x;                 // [0, 256*4*16)
    int kt = idx & 15, mat = (idx >> 4) & 3, bl = idx >> 6;
    const float* src = mat == 0 ? W0 : mat == 1 ? W1 : mat == 2 ? W2 : W3;
    int tid = threadIdx.x;
    for (int i = tid; i < 32 * 32; i += 256) {
        int r = i >> 5, c4 = i & 31;
        const float* p = src + (size_t)((r >> 3) * 2048 + bl * 8 + (r & 7)) * 2048 + kt * 128 + c4 * 4;
        float4 v = *(const float4*)p;
        lw[r][c4 * 4 + 0] = v.x; lw[r][c4 * 4 + 1] = v.y;
        lw[r][c4 * 4 + 2] = v.z; lw[r][c4 * 4 + 3] = v.w;
    }
    __syncthreads();
    if (tid < 128) {
        int gp = tid >> 6, lane = tid & 63;
        int r = (2 * gp + ((lane & 15) >> 3)) * 8 + (lane & 7);
        int k0 = (lane >> 4) * 32;
        float mx = 0.f;
#pragma unroll
        for (int e = 0; e < 32; ++e) mx = fmaxf(mx, fabsf(lw[r][k0 + e]));
        int ee = -127;
        if (mx > 0.f) {
            ee = (int)ceilf(log2f(mx * (1.0f / 6.0f)));
            if (ee < -127) ee = -127;
            if (ee > 127) ee = 127;
        }
        float inv = exp2f((float)(-ee));
        unsigned wd[4];
#pragma unroll
        for (int d = 0; d < 4; ++d) {
            unsigned acc = 0;
#pragma unroll
            for (int bi = 0; bi < 4; ++bi) {
                float v0 = lw[r][k0 + d * 8 + 2 * bi] * inv;
                float v1 = lw[r][k0 + d * 8 + 2 * bi + 1] * inv;
                acc |= (q_e2m1(v0) << (bi * 8)) | (q_e2m1(v1) << (bi * 8 + 4));
            }
            wd[d] = acc;
        }
        size_t wo = (size_t)bl * 131072 + (((size_t)(mat * 2 + gp) * 16 + (size_t)kt) * 64 + lane) * 16;
        *(uint4*)(Wp4 + wo) = make_uint4(wd[0], wd[1], wd[2], wd[3]);
        scl[(((size_t)bl * 4 + mat) * 2 + gp) * 1024 + (size_t)lane * 16 + kt] = (uchar)(ee + 127);
    }
}

__global__ void k_bias(const float* __restrict__ bi0, const float* __restrict__ bh0,
                       const float* __restrict__ bi1, const float* __restrict__ bh1,
                       float* __restrict__ bias0, float* __restrict__ bias1) {
    int i = blockIdx.x * blockDim.x + threadIdx.x;
    if (i < 4 * FDIM) {
        bias0[i] = bi0[i] + bh0[i];
        bias1[i] = bi1[i] + bh1[i];
    }
}

// ---------------- input 1x1 conv -> seq layout [t][b][2048] fp8 (x4) ----------------
__global__ __launch_bounds__(256) void k_seqprep(const float* __restrict__ x,
                                                 const float* __restrict__ w_in,
                                                 const float* __restrict__ b_in,
                                                 uchar* __restrict__ seqb) {
    int h = blockIdx.x >> 4, b = blockIdx.x & 15;
    __shared__ float xs[256][32];
    __shared__ float wl[64][257];
    int tid = threadIdx.x;
    for (int i = tid; i < 256 * 32; i += 256) {
        int c = i >> 5, w = i & 31;
        xs[c][w] = x[(((size_t)b * 256 + c) * 32 + h) * 32 + w];
    }
    for (int i = tid; i < 64 * 256; i += 256) {
        int cb = i >> 8, c = i & 255;
        wl[cb][c] = w_in[i];
    }
    __syncthreads();
    int w = (tid * 8) >> 6, cb0 = (tid * 8) & 63;
    float acc[8];
#pragma unroll
    for (int j = 0; j < 8; ++j) acc[j] = b_in[cb0 + j];
    for (int c = 0; c < 256; ++c) {
        float xv = xs[c][w];
#pragma unroll
        for (int j = 0; j < 8; ++j) acc[j] += xv * wl[cb0 + j][c];
    }
    unsigned lo = 0, hi2 = 0;
#pragma unroll
    for (int j = 0; j < 4; ++j) lo |= f2fp8(acc[j] * 4.0f) << (j * 8);
#pragma unroll
    for (int j = 0; j < 4; ++j) hi2 |= f2fp8(acc[4 + j] * 4.0f) << (j * 8);
    *(uint2*)(seqb + ((size_t)h * 16 + b) * FDIM + tid * 8) = make_uint2(lo, hi2);
}

// ---------------- persistent LSTM: LDS-resident fp4 weights ----------------
// 8 waves: gp = w&1 (gate pair), m = (w>>1)&1 (ih/hh), kh = w>>2 (K-half)
// wave 0: sole L3 poller (64 lanes x 64 counter lines) -> LDS flag release
// wave 7: sole producer tail (gate update, h publish, wave-local drain, 1 arrival RMW)
__global__ __launch_bounds__(512, 1) void k_lstm(const uchar* __restrict__ Wp4,
                                                 const uchar* __restrict__ scl,
                                                 const float* __restrict__ bias0,
                                                 const float* __restrict__ bias1,
                                                 const uchar* __restrict__ seqb,
                                                 uchar* __restrict__ H0, uchar* __restrict__ H1,
                                                 u16* __restrict__ seqout,
                                                 unsigned* __restrict__ cnts) {
    __shared__ uchar wlds[131072];            // [mat*2+gp][kt][lane*16]
    __shared__ float gbuf[2][8][16][16];      // cell-parity double buffer
    __shared__ u64 hs_st[16];
    __shared__ unsigned flagLDS;
    const int tid = threadIdx.x, lane = tid & 63, w = tid >> 6;
    const int gp = w & 1, m = (w >> 1) & 1, kh = w >> 2;
    const int bl = blockIdx.x;
    const size_t BF = (size_t)16 * FDIM;

    {
        const uchar* src = Wp4 + (size_t)bl * 131072;
        for (int i = tid; i < 8192; i += 512)
            *(uint4*)(wlds + (size_t)i * 16) = *(const uint4*)(src + (size_t)i * 16);
    }
    uint4 scl0 = *(const uint4*)(scl + (((size_t)bl * 4 + m) * 2 + gp) * 1024 + (size_t)lane * 16);
    uint4 scl1 = *(const uint4*)(scl + (((size_t)bl * 4 + 2 + m) * 2 + gp) * 1024 + (size_t)lane * 16);

    // wave-7 tail state: per-lane 2 (b,f) pairs; b = lane>>2, f = (lane&3)*2 + i
    float bw0[2][4], bw1[2][4];
    float cs0[2] = {0.f, 0.f}, cs1[2] = {0.f, 0.f};
    if (w == 7) {
        const int f0 = (lane & 3) * 2;
#pragma unroll
        for (int i = 0; i < 2; ++i) {
            int col = bl * 8 + f0 + i;
#pragma unroll
            for (int g = 0; g < 4; ++g) {
                bw0[i][g] = bias0[g * FDIM + col];
                bw1[i][g] = bias1[g * FDIM + col];
            }
        }
    }
    if (tid == 0) flagLDS = 0;
    __syncthreads();

    const int b16 = lane & 15, kq = lane >> 4;
    for (int c = 0; c < NCELL; ++c) {
        const int s = c >> 1, isL1 = c & 1, par = c & 1;
        const uchar* xsrc = isL1 ? (H0 + (size_t)(s + 1) * BF)
                          : (s < 32 ? (seqb + (size_t)s * BF) : (H1 + (size_t)s * BF));
        const uchar* hsrc = isL1 ? (H1 + (size_t)s * BF) : (H0 + (size_t)s * BF);
        const uchar* asrc = m ? hsrc : xsrc;
        // dependency targets (cells < tgt complete): ih fresh, hh 2 cells old
        const int tgt = m ? (c - 1) : ((isL1 || s >= 32) ? c : 0);
        if (w == 0) {
            if (tgt > 0) {
                const unsigned need = 4u * (unsigned)tgt;
                while (__hip_atomic_load(cnts + (size_t)lane * 32,
                                         __ATOMIC_RELAXED, __HIP_MEMORY_SCOPE_AGENT) < need)
                    __builtin_amdgcn_s_sleep(2);
                if (lane == 0)
                    __hip_atomic_store(&flagLDS, (unsigned)tgt,
                                       __ATOMIC_RELAXED, __HIP_MEMORY_SCOPE_WORKGROUP);
            }
        } else if (tgt > 0) {
            while (__hip_atomic_load(&flagLDS, __ATOMIC_RELAXED,
                                     __HIP_MEMORY_SCOPE_WORKGROUP) < (unsigned)tgt)
                __builtin_amdgcn_s_sleep(1);
        }
        asm volatile("" ::: "memory");

        const uchar* ap = asrc + b16 * 2048 + kq * 32;
        const uchar* bp = wlds + (size_t)((isL1 * 2 + m) * 2 + gp) * 16384 + lane * 16;
        uint4 sv = isL1 ? scl1 : scl0;
        unsigned sw0 = kh ? sv.z : sv.x;
        unsigned sw1 = kh ? sv.w : sv.y;

        uint4 A[8][2];
#pragma unroll
        for (int t = 0; t < 8; ++t) {
            A[t][0] = *(const uint4*)(ap + (kh * 8 + t) * 128);
            A[t][1] = *(const uint4*)(ap + (kh * 8 + t) * 128 + 16);
        }
        f32x4 acc0 = {0.f, 0.f, 0.f, 0.f}, acc1 = {0.f, 0.f, 0.f, 0.f};
#define MF(T, SW, J)                                                                   \
        {                                                                              \
            uint4 alo = A[T][0], ahi = A[T][1];                                        \
            uint4 bb = *(const uint4*)(bp + (kh * 8 + (T)) * 1024);                    \
            i8v av = {(int)alo.x, (int)alo.y, (int)alo.z, (int)alo.w,                  \
                      (int)ahi.x, (int)ahi.y, (int)ahi.z, (int)ahi.w};                 \
            i8v bv = {(int)bb.x, (int)bb.y, (int)bb.z, (int)bb.w, 0, 0, 0, 0};         \
            if ((T) & 1)                                                               \
                acc1 = __builtin_amdgcn_mfma_scale_f32_16x16x128_f8f6f4(               \
                    av, bv, acc1, 0, 4, 0, 127, J, (int)(SW));                         \
            else                                                                       \
                acc0 = __builtin_amdgcn_mfma_scale_f32_16x16x128_f8f6f4(               \
                    av, bv, acc0, 0, 4, 0, 127, J, (int)(SW));                         \
        }
        MF(0, sw0, 0); MF(1, sw0, 1); MF(2, sw0, 2); MF(3, sw0, 3);
        MF(4, sw1, 0); MF(5, sw1, 1); MF(6, sw1, 2); MF(7, sw1, 3);
#undef MF
        f32x4 acc = acc0 + acc1;
#pragma unroll
        for (int i = 0; i < 4; ++i) gbuf[par][w][kq * 4 + i][b16] = acc[i];
        __syncthreads();   // S1 — the only block-wide barrier per cell

        if (w == 7) {
            // gate update for 2 (b,f) pairs per lane
            const int b = lane >> 2, f0 = (lane & 3) * 2;
            u16 hb2 = 0;
            float hnv[2];
#pragma unroll
            for (int i = 0; i < 2; ++i) {
                const int f = f0 + i;
                float gv[4];
#pragma unroll
                for (int g = 0; g < 4; ++g) {
                    int gpp = g >> 1, jl = ((g & 1) << 3) | f;
                    gv[g] = (gbuf[par][gpp][b][jl] + gbuf[par][gpp + 2][b][jl]
                           + gbuf[par][gpp + 4][b][jl] + gbuf[par][gpp + 6][b][jl]) * 0.25f
                           + (isL1 ? bw1[i][g] : bw0[i][g]);
                }
                float co = isL1 ? cs1[i] : cs0[i];
                float cn = sigm(gv[1]) * co + sigm(gv[0]) * tanh_f(gv[2]);
                float hn = sigm(gv[3]) * tanh_f(cn);
                if (isL1) cs1[i] = cn; else cs0[i] = cn;
                hb2 |= (u16)(f2fp8(hn * 4.0f) << (8 * i));
                hnv[i] = hn;
            }
            *(u16*)((uchar*)&hs_st[b] + f0) = hb2;
            asm volatile("s_waitcnt lgkmcnt(0)" ::: "memory");
            if (lane < 16) {
                uchar* hdst = (isL1 ? H1 : H0) + (size_t)(s + 1) * BF;
                __hip_atomic_store((u64*)(hdst + (size_t)lane * FDIM + bl * 8), hs_st[lane],
                                   __ATOMIC_RELAXED, __HIP_MEMORY_SCOPE_AGENT);
            }
            asm volatile("s_waitcnt vmcnt(0)" ::: "memory");   // wave-local drain only
            if (lane == 0)
                __hip_atomic_fetch_add(cnts + (size_t)(bl & 63) * 32, 1u,
                                       __ATOMIC_RELAXED, __HIP_MEMORY_SCOPE_AGENT);
            if (isL1 && s >= 31) {   // off the notify path
                unsigned pk = (unsigned)f2b(hnv[0]) | ((unsigned)f2b(hnv[1]) << 16);
                *(unsigned*)(seqout + (size_t)(s - 31) * BF + (size_t)b * FDIM + bl * 8 + f0) = pk;
            }
        }
    }
}

// ---------------- copy x into top half of output ----------------
__global__ void k_copyx(const float* __restrict__ x, float* __restrict__ out) {
    size_t n = (size_t)4096 * 256;
    size_t stride = (size_t)gridDim.x * blockDim.x;
    for (size_t i = (size_t)blockIdx.x * blockDim.x + threadIdx.x; i < n; i += stride) {
        size_t bc = i >> 8, r = i & 255;
        ((float4*)out)[bc * 512 + r] = ((const float4*)x)[i];
    }
}

// ---------------- output 1x1 conv into bottom half ----------------
__global__ __launch_bounds__(256) void k_convout(const u16* __restrict__ seqout,
                                                 const float* __restrict__ w_out,
                                                 const float* __restrict__ b_out,
                                                 float* __restrict__ out) {
    int s = blockIdx.x >> 4, b = blockIdx.x & 15;
    __shared__ float srow[2048];
    int tid = threadIdx.x;
    for (int i = tid; i < 2048; i += 256) srow[i] = b2f(seqout[((size_t)s * 16 + b) * FDIM + i]);
    __syncthreads();
    int o = tid;
    float bo = b_out[o];
    float wreg[64];
#pragma unroll
    for (int cb = 0; cb < 64; ++cb) wreg[cb] = w_out[o * 64 + cb];
    for (int w4 = 0; w4 < 8; ++w4) {
        float ac0 = bo, ac1 = bo, ac2 = bo, ac3 = bo;
#pragma unroll
        for (int cb = 0; cb < 64; ++cb) {
            float wv = wreg[cb];
            ac0 += srow[(w4 * 4 + 0) * 64 + cb] * wv;
            ac1 += srow[(w4 * 4 + 1) * 64 + cb] * wv;
            ac2 += srow[(w4 * 4 + 2) * 64 + cb] * wv;
            ac3 += srow[(w4 * 4 + 3) * 64 + cb] * wv;
        }
        float4 v; v.x = ac0; v.y = ac1; v.z = ac2; v.w = ac3;
        *(float4*)&out[(((size_t)b * 256 + o) * 64 + 32 + s) * 32 + w4 * 4] = v;
    }
}

extern "C" void kernel_launch(void* const* d_in, const int* in_sizes, int n_in,
                              void* d_out, int out_size, void* d_ws, size_t ws_size,
                              hipStream_t stream) {
    const float* x    = (const float*)d_in[0];
    const float* w_in = (const float*)d_in[1];
    const float* b_in = (const float*)d_in[2];
    const float* Wih0 = (const float*)d_in[3];
    const float* Whh0 = (const float*)d_in[4];
    const float* bih0 = (const float*)d_in[5];
    const float* bhh0 = (const float*)d_in[6];
    const float* Wih1 = (const float*)d_in[7];
    const float* Whh1 = (const float*)d_in[8];
    const float* bih1 = (const float*)d_in[9];
    const float* bhh1 = (const float*)d_in[10];
    const float* wout = (const float*)d_in[11];
    const float* bout = (const float*)d_in[12];
    float* out = (float*)d_out;
    char* ws = (char*)d_ws;
    const size_t BF = (size_t)16 * FDIM;

    uchar* Wp4 = (uchar*)ws;
    size_t off = (size_t)NBLK * 131072;                       // 32 MiB packed fp4 weights
    uchar* scl = (uchar*)(ws + off); off += (size_t)NBLK * 4 * 2 * 1024;   // 2 MiB scales
    float* bias0 = (float*)(ws + off); off += 4 * FDIM * 4;
    float* bias1 = (float*)(ws + off); off += 4 * FDIM * 4;
    uchar* seqb = (uchar*)(ws + off); off += (size_t)32 * BF;              // 1 MiB
    u16* seqout = (u16*)(ws + off); off += (size_t)32 * BF * 2;            // 2 MiB
    uchar* H0 = (uchar*)(ws + off); off += (size_t)64 * BF;                // 2 MiB (rotating slots)
    uchar* H1 = (uchar*)(ws + off); off += (size_t)64 * BF;                // 2 MiB
    off = (off + 127) & ~(size_t)127;
    unsigned* cnts = (unsigned*)(ws + off); size_t cntoff = off; off += 64 * 32 * 4;  // 64 lines

    // zero: H0 slot0, H1 slot0, barrier counters (all in-graph, per replay)
    hipMemsetAsync(H0, 0, BF, stream);
    hipMemsetAsync(H1, 0, BF, stream);
    hipMemsetAsync(ws + cntoff, 0, off - cntoff, stream);

    k_pack4<<<256 * 4 * 16, 256, 0, stream>>>(Wih0, Whh0, Wih1, Whh1, Wp4, scl);
    k_bias<<<32, 256, 0, stream>>>(bih0, bhh0, bih1, bhh1, bias0, bias1);
    k_seqprep<<<512, 256, 0, stream>>>(x, w_in, b_in, seqb);
    k_lstm<<<NBLK, 512, 0, stream>>>(Wp4, scl, bias0, bias1, seqb, H0, H1, seqout, cnts);
    k_copyx<<<2048, 256, 0, stream>>>(x, out);
    k_convout<<<512, 256, 0, stream>>>(seqout, wout, bout, out);
}

// Round 8
// 629.190 us; speedup vs baseline: 1.7423x; 1.3919x over previous
//
#include <hip/hip_runtime.h>
#include <hip/hip_bf16.h>

typedef unsigned short u16;
typedef unsigned char uchar;
typedef unsigned long long u64;
typedef float f32x4 __attribute__((ext_vector_type(4)));
typedef int i8v __attribute__((ext_vector_type(8)));

#define FDIM 2048
#define NBLK 256
#define NCELL 126

__device__ __forceinline__ u16 f2b(float x) {
    __hip_bfloat16 h = __float2bfloat16(x);
    return __builtin_bit_cast(u16, h);
}
__device__ __forceinline__ float b2f(u16 u) {
    __hip_bfloat16 h = __builtin_bit_cast(__hip_bfloat16, u);
    return __bfloat162float(h);
}
__device__ __forceinline__ float sigm(float x) { return 1.0f / (1.0f + __expf(-x)); }
__device__ __forceinline__ float tanh_f(float x) { return 1.0f - 2.0f / (__expf(2.0f * x) + 1.0f); }

// OCP e4m3 encode (RNE), saturate to 448.
__device__ __forceinline__ unsigned f2fp8(float x) {
    unsigned u = __builtin_bit_cast(unsigned, x);
    unsigned s = (u >> 24) & 0x80u;
    unsigned mag = u & 0x7fffffffu;
    if (mag >= 0x43E80000u) return s | 0x7Eu;
    int e = (int)(mag >> 23) - 127;
    if (e >= -6) {
        unsigned m = mag + 0x7FFFFu + ((mag >> 20) & 1u);
        unsigned e8 = (m >> 23) - 127 + 7;
        unsigned m3 = (m >> 20) & 7u;
        if (e8 >= 16u) return s | 0x7Eu;
        return s | (e8 << 3) | m3;
    }
    float ax = __builtin_bit_cast(float, mag);
    int d = (int)__builtin_rintf(ax * 512.0f);
    return s | (unsigned)d;
}

// e2m1 (fp4) quantize of v (|v|<=6 after scaling): returns 4-bit code
__device__ __forceinline__ unsigned q_e2m1(float v) {
    unsigned s = (v < 0.f) ? 8u : 0u;
    float a = fabsf(v);
    unsigned q;
    if (a < 0.25f) q = 0;
    else if (a < 0.75f) q = 1;
    else if (a < 1.25f) q = 2;
    else if (a < 1.75f) q = 3;
    else if (a < 2.5f)  q = 4;
    else if (a < 3.5f)  q = 5;
    else if (a < 5.0f)  q = 6;
    else q = 7;
    return s | q;
}

// ---------------- weight pack: fp32 -> MX fp4 (E8M0 per-32 scales), MFMA fragment order ----------
__global__ __launch_bounds__(256) void k_pack4(const float* __restrict__ W0, const float* __restrict__ W1,
                                               const float* __restrict__ W2, const float* __restrict__ W3,
                                               uchar* __restrict__ Wp4, uchar* __restrict__ scl) {
    __shared__ float lw[32][132];
    int idx = blockIdx.x;                 // [0, 256*4*16)
    int kt = idx & 15, mat = (idx >> 4) & 3, bl = idx >> 6;
    const float* src = mat == 0 ? W0 : mat == 1 ? W1 : mat == 2 ? W2 : W3;
    int tid = threadIdx.x;
    for (int i = tid; i < 32 * 32; i += 256) {
        int r = i >> 5, c4 = i & 31;
        const float* p = src + (size_t)((r >> 3) * 2048 + bl * 8 + (r & 7)) * 2048 + kt * 128 + c4 * 4;
        float4 v = *(const float4*)p;
        lw[r][c4 * 4 + 0] = v.x; lw[r][c4 * 4 + 1] = v.y;
        lw[r][c4 * 4 + 2] = v.z; lw[r][c4 * 4 + 3] = v.w;
    }
    __syncthreads();
    if (tid < 128) {
        int gp = tid >> 6, lane = tid & 63;
        int r = (2 * gp + ((lane & 15) >> 3)) * 8 + (lane & 7);
        int k0 = (lane >> 4) * 32;
        float mx = 0.f;
#pragma unroll
        for (int e = 0; e < 32; ++e) mx = fmaxf(mx, fabsf(lw[r][k0 + e]));
        int ee = -127;
        if (mx > 0.f) {
            ee = (int)ceilf(log2f(mx * (1.0f / 6.0f)));
            if (ee < -127) ee = -127;
            if (ee > 127) ee = 127;
        }
        float inv = exp2f((float)(-ee));
        unsigned wd[4];
#pragma unroll
        for (int d = 0; d < 4; ++d) {
            unsigned acc = 0;
#pragma unroll
            for (int bi = 0; bi < 4; ++bi) {
                float v0 = lw[r][k0 + d * 8 + 2 * bi] * inv;
                float v1 = lw[r][k0 + d * 8 + 2 * bi + 1] * inv;
                acc |= (q_e2m1(v0) << (bi * 8)) | (q_e2m1(v1) << (bi * 8 + 4));
            }
            wd[d] = acc;
        }
        size_t wo = (size_t)bl * 131072 + (((size_t)(mat * 2 + gp) * 16 + (size_t)kt) * 64 + lane) * 16;
        *(uint4*)(Wp4 + wo) = make_uint4(wd[0], wd[1], wd[2], wd[3]);
        scl[(((size_t)bl * 4 + mat) * 2 + gp) * 1024 + (size_t)lane * 16 + kt] = (uchar)(ee + 127);
    }
}

__global__ void k_bias(const float* __restrict__ bi0, const float* __restrict__ bh0,
                       const float* __restrict__ bi1, const float* __restrict__ bh1,
                       float* __restrict__ bias0, float* __restrict__ bias1) {
    int i = blockIdx.x * blockDim.x + threadIdx.x;
    if (i < 4 * FDIM) {
        bias0[i] = bi0[i] + bh0[i];
        bias1[i] = bi1[i] + bh1[i];
    }
}

// ---------------- input 1x1 conv -> seq slots in MFMA-FRAGMENT layout, fp8 (x4) ----------------
// slot layout: [kt(16)][lane(64)][32B], k = kt*128 + (lane>>4)*32 + byte, row b = lane&15
__global__ __launch_bounds__(256) void k_seqprep(const float* __restrict__ x,
                                                 const float* __restrict__ w_in,
                                                 const float* __restrict__ b_in,
                                                 uchar* __restrict__ seqb) {
    int h = blockIdx.x >> 4, b = blockIdx.x & 15;
    __shared__ float xs[256][32];
    __shared__ float wl[64][257];
    int tid = threadIdx.x;
    for (int i = tid; i < 256 * 32; i += 256) {
        int c = i >> 5, w = i & 31;
        xs[c][w] = x[(((size_t)b * 256 + c) * 32 + h) * 32 + w];
    }
    for (int i = tid; i < 64 * 256; i += 256) {
        int cb = i >> 8, c = i & 255;
        wl[cb][c] = w_in[i];
    }
    __syncthreads();
    int w = (tid * 8) >> 6, cb0 = (tid * 8) & 63;
    float acc[8];
#pragma unroll
    for (int j = 0; j < 8; ++j) acc[j] = b_in[cb0 + j];
    for (int c = 0; c < 256; ++c) {
        float xv = xs[c][w];
#pragma unroll
        for (int j = 0; j < 8; ++j) acc[j] += xv * wl[cb0 + j][c];
    }
    unsigned lo = 0, hi2 = 0;
#pragma unroll
    for (int j = 0; j < 4; ++j) lo |= f2fp8(acc[j] * 4.0f) << (j * 8);
#pragma unroll
    for (int j = 0; j < 4; ++j) hi2 |= f2fp8(acc[4 + j] * 4.0f) << (j * 8);
    // k = tid*8 -> kt = tid>>4, kq = (tid>>2)&3, e0 = (tid&3)*8
    int kt = tid >> 4, kq = (tid >> 2) & 3, e0 = (tid & 3) * 8;
    uchar* dst = seqb + (size_t)h * 32768 + (size_t)kt * 2048 + (size_t)(b + 16 * kq) * 32 + e0;
    *(uint2*)dst = make_uint2(lo, hi2);
}

// ---------------- persistent LSTM: LDS-resident fp4 weights, fragment-layout activations -------
// 8 waves: gp = w&1 (gate pair), m = (w>>1)&1 (ih/hh), kh = w>>2 (K-half)
// wave 0: sole L3 poller (64 lanes x 64 counter lines) -> LDS flag release
// wave 7: sole producer tail (gate update, h publish, wave-local drain, 1 arrival RMW)
__global__ __launch_bounds__(512, 1) void k_lstm(const uchar* __restrict__ Wp4,
                                                 const uchar* __restrict__ scl,
                                                 const float* __restrict__ bias0,
                                                 const float* __restrict__ bias1,
                                                 const uchar* __restrict__ seqb,
                                                 uchar* __restrict__ H0, uchar* __restrict__ H1,
                                                 u16* __restrict__ seqout,
                                                 unsigned* __restrict__ cnts) {
    __shared__ uchar wlds[131072];            // [mat*2+gp][kt][lane*16]
    __shared__ float gbuf[2][8][16][20];      // cell-parity dbuf; col pad 16->20 (bank fix)
    __shared__ u64 hs_st[16];
    __shared__ unsigned flagLDS;
    const int tid = threadIdx.x, lane = tid & 63, w = tid >> 6;
    const int gp = w & 1, m = (w >> 1) & 1, kh = w >> 2;
    const int bl = blockIdx.x;
    const size_t BF = (size_t)16 * FDIM;

    {
        const uchar* src = Wp4 + (size_t)bl * 131072;
        for (int i = tid; i < 8192; i += 512)
            *(uint4*)(wlds + (size_t)i * 16) = *(const uint4*)(src + (size_t)i * 16);
    }
    uint4 scl0 = *(const uint4*)(scl + (((size_t)bl * 4 + m) * 2 + gp) * 1024 + (size_t)lane * 16);
    uint4 scl1 = *(const uint4*)(scl + (((size_t)bl * 4 + 2 + m) * 2 + gp) * 1024 + (size_t)lane * 16);

    // wave-7 tail state: per-lane 2 (b,f) pairs; b = lane>>2, f = (lane&3)*2 + i
    float bw0[2][4], bw1[2][4];
    float cs0[2] = {0.f, 0.f}, cs1[2] = {0.f, 0.f};
    if (w == 7) {
        const int f0 = (lane & 3) * 2;
#pragma unroll
        for (int i = 0; i < 2; ++i) {
            int col = bl * 8 + f0 + i;
#pragma unroll
            for (int g = 0; g < 4; ++g) {
                bw0[i][g] = bias0[g * FDIM + col];
                bw1[i][g] = bias1[g * FDIM + col];
            }
        }
    }
    if (tid == 0) flagLDS = 0;
    __syncthreads();

    const int b16 = lane & 15, kq = lane >> 4;
    for (int c = 0; c < NCELL; ++c) {
        const int s = c >> 1, isL1 = c & 1, par = c & 1;
        const uchar* xsrc = isL1 ? (H0 + (size_t)(s + 1) * BF)
                          : (s < 32 ? (seqb + (size_t)s * BF) : (H1 + (size_t)s * BF));
        const uchar* hsrc = isL1 ? (H1 + (size_t)s * BF) : (H0 + (size_t)s * BF);
        const uchar* asrc = m ? hsrc : xsrc;
        // dependency targets (cells < tgt complete): ih fresh, hh 2 cells old
        const int tgt = m ? (c - 1) : ((isL1 || s >= 32) ? c : 0);
        if (w == 0) {
            if (tgt > 0) {
                const unsigned need = 4u * (unsigned)tgt;
                while (__hip_atomic_load(cnts + (size_t)lane * 32,
                                         __ATOMIC_RELAXED, __HIP_MEMORY_SCOPE_AGENT) < need)
                    __builtin_amdgcn_s_sleep(2);
                if (lane == 0)
                    __hip_atomic_store(&flagLDS, (unsigned)tgt,
                                       __ATOMIC_RELAXED, __HIP_MEMORY_SCOPE_WORKGROUP);
            }
        } else if (tgt > 0) {
            while (__hip_atomic_load(&flagLDS, __ATOMIC_RELAXED,
                                     __HIP_MEMORY_SCOPE_WORKGROUP) < (unsigned)tgt)
                __builtin_amdgcn_s_sleep(1);
        }
        asm volatile("" ::: "memory");

        // fragment-layout A loads: 64 lanes x 32B contiguous per t (fully coalesced)
        const uchar* ap = asrc + (size_t)lane * 32;
        const uchar* bp = wlds + (size_t)((isL1 * 2 + m) * 2 + gp) * 16384 + lane * 16;
        uint4 sv = isL1 ? scl1 : scl0;
        unsigned sw0 = kh ? sv.z : sv.x;
        unsigned sw1 = kh ? sv.w : sv.y;

        uint4 A[8][2];
#pragma unroll
        for (int t = 0; t < 8; ++t) {
            A[t][0] = *(const uint4*)(ap + (size_t)(kh * 8 + t) * 2048);
            A[t][1] = *(const uint4*)(ap + (size_t)(kh * 8 + t) * 2048 + 16);
        }
        f32x4 acc0 = {0.f, 0.f, 0.f, 0.f}, acc1 = {0.f, 0.f, 0.f, 0.f};
#define MF(T, SW, J)                                                                   \
        {                                                                              \
            uint4 alo = A[T][0], ahi = A[T][1];                                        \
            uint4 bb = *(const uint4*)(bp + (kh * 8 + (T)) * 1024);                    \
            i8v av = {(int)alo.x, (int)alo.y, (int)alo.z, (int)alo.w,                  \
                      (int)ahi.x, (int)ahi.y, (int)ahi.z, (int)ahi.w};                 \
            i8v bv = {(int)bb.x, (int)bb.y, (int)bb.z, (int)bb.w, 0, 0, 0, 0};         \
            if ((T) & 1)                                                               \
                acc1 = __builtin_amdgcn_mfma_scale_f32_16x16x128_f8f6f4(               \
                    av, bv, acc1, 0, 4, 0, 127, J, (int)(SW));                         \
            else                                                                       \
                acc0 = __builtin_amdgcn_mfma_scale_f32_16x16x128_f8f6f4(               \
                    av, bv, acc0, 0, 4, 0, 127, J, (int)(SW));                         \
        }
        MF(0, sw0, 0); MF(1, sw0, 1); MF(2, sw0, 2); MF(3, sw0, 3);
        MF(4, sw1, 0); MF(5, sw1, 1); MF(6, sw1, 2); MF(7, sw1, 3);
#undef MF
        f32x4 acc = acc0 + acc1;
#pragma unroll
        for (int i = 0; i < 4; ++i) gbuf[par][w][kq * 4 + i][b16] = acc[i];
        __syncthreads();   // S1 — the only block-wide barrier per cell

        if (w == 7) {
            // gate update for 2 (b,f) pairs per lane
            const int b = lane >> 2, f0 = (lane & 3) * 2;
            u16 hb2 = 0;
            float hnv[2];
#pragma unroll
            for (int i = 0; i < 2; ++i) {
                const int f = f0 + i;
                float gv[4];
#pragma unroll
                for (int g = 0; g < 4; ++g) {
                    int gpp = g >> 1, jl = ((g & 1) << 3) | f;
                    gv[g] = (gbuf[par][gpp][b][jl] + gbuf[par][gpp + 2][b][jl]
                           + gbuf[par][gpp + 4][b][jl] + gbuf[par][gpp + 6][b][jl]) * 0.25f
                           + (isL1 ? bw1[i][g] : bw0[i][g]);
                }
                float co = isL1 ? cs1[i] : cs0[i];
                float cn = sigm(gv[1]) * co + sigm(gv[0]) * tanh_f(gv[2]);
                float hn = sigm(gv[3]) * tanh_f(cn);
                if (isL1) cs1[i] = cn; else cs0[i] = cn;
                hb2 |= (u16)(f2fp8(hn * 4.0f) << (8 * i));
                hnv[i] = hn;
            }
            *(u16*)((uchar*)&hs_st[b] + f0) = hb2;
            asm volatile("s_waitcnt lgkmcnt(0)" ::: "memory");
            if (lane < 16) {
                // fragment-layout publish: k = bl*8..bl*8+8 -> kt0=bl>>4, kq0=(bl>>2)&3, e00=(bl&3)*8
                uchar* hdst = (isL1 ? H1 : H0) + (size_t)(s + 1) * BF;
                size_t o = (size_t)(bl >> 4) * 2048 + (size_t)((bl >> 2) & 3) * 512
                         + (size_t)(bl & 3) * 8 + (size_t)lane * 32;
                __hip_atomic_store((u64*)(hdst + o), hs_st[lane],
                                   __ATOMIC_RELAXED, __HIP_MEMORY_SCOPE_AGENT);
            }
            asm volatile("s_waitcnt vmcnt(0)" ::: "memory");   // wave-local drain only
            if (lane == 0)
                __hip_atomic_fetch_add(cnts + (size_t)(bl & 63) * 32, 1u,
                                       __ATOMIC_RELAXED, __HIP_MEMORY_SCOPE_AGENT);
            if (isL1 && s >= 31) {   // off the notify path (row-major bf16 for convout)
                unsigned pk = (unsigned)f2b(hnv[0]) | ((unsigned)f2b(hnv[1]) << 16);
                *(unsigned*)(seqout + (size_t)(s - 31) * BF + (size_t)b * FDIM + bl * 8 + f0) = pk;
            }
        }
    }
}

// ---------------- copy x into top half of output ----------------
__global__ void k_copyx(const float* __restrict__ x, float* __restrict__ out) {
    size_t n = (size_t)4096 * 256;
    size_t stride = (size_t)gridDim.x * blockDim.x;
    for (size_t i = (size_t)blockIdx.x * blockDim.x + threadIdx.x; i < n; i += stride) {
        size_t bc = i >> 8, r = i & 255;
        ((float4*)out)[bc * 512 + r] = ((const float4*)x)[i];
    }
}

// ---------------- output 1x1 conv into bottom half ----------------
__global__ __launch_bounds__(256) void k_convout(const u16* __restrict__ seqout,
                                                 const float* __restrict__ w_out,
                                                 const float* __restrict__ b_out,
                                                 float* __restrict__ out) {
    int s = blockIdx.x >> 4, b = blockIdx.x & 15;
    __shared__ float srow[2048];
    int tid = threadIdx.x;
    for (int i = tid; i < 2048; i += 256) srow[i] = b2f(seqout[((size_t)s * 16 + b) * FDIM + i]);
    __syncthreads();
    int o = tid;
    float bo = b_out[o];
    float wreg[64];
#pragma unroll
    for (int cb = 0; cb < 64; ++cb) wreg[cb] = w_out[o * 64 + cb];
    for (int w4 = 0; w4 < 8; ++w4) {
        float ac0 = bo, ac1 = bo, ac2 = bo, ac3 = bo;
#pragma unroll
        for (int cb = 0; cb < 64; ++cb) {
            float wv = wreg[cb];
            ac0 += srow[(w4 * 4 + 0) * 64 + cb] * wv;
            ac1 += srow[(w4 * 4 + 1) * 64 + cb] * wv;
            ac2 += srow[(w4 * 4 + 2) * 64 + cb] * wv;
            ac3 += srow[(w4 * 4 + 3) * 64 + cb] * wv;
        }
        float4 v; v.x = ac0; v.y = ac1; v.z = ac2; v.w = ac3;
        *(float4*)&out[(((size_t)b * 256 + o) * 64 + 32 + s) * 32 + w4 * 4] = v;
    }
}

extern "C" void kernel_launch(void* const* d_in, const int* in_sizes, int n_in,
                              void* d_out, int out_size, void* d_ws, size_t ws_size,
                              hipStream_t stream) {
    const float* x    = (const float*)d_in[0];
    const float* w_in = (const float*)d_in[1];
    const float* b_in = (const float*)d_in[2];
    const float* Wih0 = (const float*)d_in[3];
    const float* Whh0 = (const float*)d_in[4];
    const float* bih0 = (const float*)d_in[5];
    const float* bhh0 = (const float*)d_in[6];
    const float* Wih1 = (const float*)d_in[7];
    const float* Whh1 = (const float*)d_in[8];
    const float* bih1 = (const float*)d_in[9];
    const float* bhh1 = (const float*)d_in[10];
    const float* wout = (const float*)d_in[11];
    const float* bout = (const float*)d_in[12];
    float* out = (float*)d_out;
    char* ws = (char*)d_ws;
    const size_t BF = (size_t)16 * FDIM;

    uchar* Wp4 = (uchar*)ws;
    size_t off = (size_t)NBLK * 131072;                       // 32 MiB packed fp4 weights
    uchar* scl = (uchar*)(ws + off); off += (size_t)NBLK * 4 * 2 * 1024;   // 2 MiB scales
    float* bias0 = (float*)(ws + off); off += 4 * FDIM * 4;
    float* bias1 = (float*)(ws + off); off += 4 * FDIM * 4;
    uchar* seqb = (uchar*)(ws + off); off += (size_t)32 * BF;              // 1 MiB
    u16* seqout = (u16*)(ws + off); off += (size_t)32 * BF * 2;            // 2 MiB
    uchar* H0 = (uchar*)(ws + off); off += (size_t)64 * BF;                // 2 MiB (rotating slots)
    uchar* H1 = (uchar*)(ws + off); off += (size_t)64 * BF;                // 2 MiB
    off = (off + 127) & ~(size_t)127;
    unsigned* cnts = (unsigned*)(ws + off); size_t cntoff = off; off += 64 * 32 * 4;  // 64 lines

    // zero: H0 slot0, H1 slot0, barrier counters (all in-graph, per replay)
    hipMemsetAsync(H0, 0, BF, stream);
    hipMemsetAsync(H1, 0, BF, stream);
    hipMemsetAsync(ws + cntoff, 0, off - cntoff, stream);

    k_pack4<<<256 * 4 * 16, 256, 0, stream>>>(Wih0, Whh0, Wih1, Whh1, Wp4, scl);
    k_bias<<<32, 256, 0, stream>>>(bih0, bhh0, bih1, bhh1, bias0, bias1);
    k_seqprep<<<512, 256, 0, stream>>>(x, w_in, b_in, seqb);
    k_lstm<<<NBLK, 512, 0, stream>>>(Wp4, scl, bias0, bias1, seqb, H0, H1, seqout, cnts);
    k_copyx<<<2048, 256, 0, stream>>>(x, out);
    k_convout<<<512, 256, 0, stream>>>(seqout, wout, bout, out);
}